// Round 1
// baseline (1207.971 us; speedup 1.0000x reference)
//
#include <hip/hip_runtime.h>
#include <math.h>

// Problem constants (Occ3D-nuScenes volume)
constexpr int   GX = 200, GY = 200, GZ = 16;
constexpr int   TOTAL = GX * GY * GZ;        // 640000 voxels
constexpr int   ND = 16;                     // feature dims
constexpr int   KW = 6;                      // window
constexpr int   NCELL = KW * KW * KW;        // 216
constexpr float VS = 0.4f;
constexpr float VMINX = -40.0f, VMINY = -40.0f, VMINZ = -1.0f;

// d_out layout: [density: TOTAL floats][feats: TOTAL*ND floats]

__global__ __launch_bounds__(256) void gv_init(float* __restrict__ out) {
    int i = blockIdx.x * 256 + threadIdx.x;
    if (i < TOTAL * (1 + ND)) {
        float v = 0.0f;
        // feats channel 15 starts at 1e-5 (reference .at[:, -1].set(1e-5))
        if (i >= TOTAL && ((i - TOTAL) & 15) == 15) v = 1e-5f;
        out[i] = v;
    }
}

__global__ __launch_bounds__(256) void gv_splat(
    const float* __restrict__ means, const float* __restrict__ covs,
    const float* __restrict__ opac,  const float* __restrict__ feats,
    float* __restrict__ out)
{
    const int g = blockIdx.x;
    __shared__ float sf[10 + ND];  // mean xyz, inv-cov 6, opacity, feat[16]
    __shared__ int   si[6];        // start xyz, end xyz

    if (threadIdx.x == 0) {
        const float* cv = covs + (size_t)g * 9;
        // symmetric 3x3: [[a,b,c],[b,d,e],[c,e,f]]
        float a = cv[0], b = cv[1], c = cv[2], d = cv[4], e = cv[5], f = cv[8];
        float A = d * f - e * e;
        float B = c * e - b * f;
        float C = b * e - c * d;
        float invdet = 1.0f / (a * A + b * B + c * C);
        float mx = means[g * 3 + 0], my = means[g * 3 + 1], mz = means[g * 3 + 2];
        sf[0] = mx; sf[1] = my; sf[2] = mz;
        sf[3] = A * invdet;                 // i00
        sf[4] = B * invdet;                 // i01
        sf[5] = C * invdet;                 // i02
        sf[6] = (a * f - c * c) * invdet;   // i11
        sf[7] = (b * c - a * e) * invdet;   // i12
        sf[8] = (a * d - b * b) * invdet;   // i22
        sf[9] = opac[g];
        float rx = 3.0f * sqrtf(a), ry = 3.0f * sqrtf(d), rz = 3.0f * sqrtf(f);
        // trunc-toward-zero int cast matches .astype(int32)
        si[0] = max(0, (int)((mx - rx - VMINX) / VS));
        si[1] = max(0, (int)((my - ry - VMINY) / VS));
        si[2] = max(0, (int)((mz - rz - VMINZ) / VS));
        si[3] = min(GX, (int)((mx + rx - VMINX) / VS) + 1);
        si[4] = min(GY, (int)((my + ry - VMINY) / VS) + 1);
        si[5] = min(GZ, (int)((mz + rz - VMINZ) / VS) + 1);
    }
    if (threadIdx.x < ND) sf[10 + threadIdx.x] = feats[(size_t)g * ND + threadIdx.x];
    __syncthreads();

    int t = threadIdx.x;
    if (t >= NCELL) return;
    int kx = t / 36;
    int r  = t - kx * 36;
    int ky = r / 6;
    int kz = r - ky * 6;
    int ix = si[0] + kx, iy = si[1] + ky, iz = si[2] + kz;
    if (ix >= si[3] || iy >= si[4] || iz >= si[5]) return;  // masked -> exact 0 contribution

    // voxel CORNER minus mean (matches reference: ix*vs + vol_min - m)
    float px = (float)ix * VS + VMINX - sf[0];
    float py = (float)iy * VS + VMINY - sf[1];
    float pz = (float)iz * VS + VMINZ - sf[2];
    float mahal = sf[3] * px * px + sf[6] * py * py + sf[8] * pz * pz
                + 2.0f * (sf[4] * px * py + sf[5] * px * pz + sf[7] * py * pz);
    float dens = sf[9] * __expf(-0.5f * mahal);

    int flat = (ix * GY + iy) * GZ + iz;
    atomicAdd(out + flat, dens);
    float* fo = out + TOTAL + (size_t)flat * ND;
#pragma unroll
    for (int c = 0; c < ND; ++c)
        atomicAdd(fo + c, dens * sf[10 + c]);
}

__global__ __launch_bounds__(256) void gv_norm(float* __restrict__ out) {
    int i = blockIdx.x * 256 + threadIdx.x;
    if (i < TOTAL * ND) {
        float den = fmaxf(out[i >> 4], 1e-6f);   // clip(density, 1e-6, None)
        out[TOTAL + i] = out[TOTAL + i] / den;
    }
}

extern "C" void kernel_launch(void* const* d_in, const int* in_sizes, int n_in,
                              void* d_out, int out_size, void* d_ws, size_t ws_size,
                              hipStream_t stream) {
    const float* means = (const float*)d_in[0];   // [N,3]
    const float* covs  = (const float*)d_in[1];   // [N,3,3]
    const float* opac  = (const float*)d_in[2];   // [N]
    const float* feats = (const float*)d_in[3];   // [N,16]
    float* out = (float*)d_out;                   // [TOTAL + TOTAL*ND]
    const int n_gauss = in_sizes[2];

    const int tot_elems = TOTAL * (1 + ND);
    gv_init<<<(tot_elems + 255) / 256, 256, 0, stream>>>(out);
    gv_splat<<<n_gauss, 256, 0, stream>>>(means, covs, opac, feats, out);
    gv_norm<<<(TOTAL * ND + 255) / 256, 256, 0, stream>>>(out);
}

// Round 2
// 146.478 us; speedup vs baseline: 8.2468x; 8.2468x over previous
//
#include <hip/hip_runtime.h>
#include <math.h>

// Problem constants (Occ3D-nuScenes volume)
constexpr int   GX = 200, GY = 200, GZ = 16;
constexpr int   TOTAL = GX * GY * GZ;        // 640000 voxels
constexpr int   ND = 16;                     // feature dims
constexpr int   KW = 6;                      // reference window: start + [0,6)
constexpr float VS = 0.4f;
constexpr float VMINX = -40.0f, VMINY = -40.0f, VMINZ = -1.0f;

// Tiling: 8x8x8 voxel tiles, each owned exclusively by one block (gather).
constexpr int   TS = 8;
constexpr int   TX = 25, TY = 25, TZ = 2;    // 200/8, 200/8, 16/8
constexpr int   NT = TX * TY * TZ;           // 1250 tiles
constexpr int   REC = 32;                    // floats per packed gaussian record
constexpr int   VPT = 2;                     // voxels per thread (512 / 256)

// d_out layout: [density: TOTAL floats][feats: TOTAL*ND floats]
// d_ws layout:  [gdata: n*REC floats][counts: NT][offsets: NT+1][cursors: NT][entries: 8n]

__global__ __launch_bounds__(256) void gv_zero(int* __restrict__ counts) {
    int i = blockIdx.x * 256 + threadIdx.x;
    if (i < NT) counts[i] = 0;
}

// Per-gaussian precompute: inverse cov, bbox, packed record; count tile overlaps.
__global__ __launch_bounds__(256) void gv_prep(
    const float* __restrict__ means, const float* __restrict__ covs,
    const float* __restrict__ opac,  const float* __restrict__ feats,
    float* __restrict__ gdata, int* __restrict__ counts, int n)
{
    int g = blockIdx.x * 256 + threadIdx.x;
    if (g >= n) return;
    const float* cv = covs + (size_t)g * 9;
    // symmetric 3x3: [[a,b,c],[b,d,e],[c,e,f]]
    float a = cv[0], b = cv[1], c = cv[2], d = cv[4], e = cv[5], f = cv[8];
    float A = d * f - e * e;
    float B = c * e - b * f;
    float C = b * e - c * d;
    float invdet = 1.0f / (a * A + b * B + c * C);
    float mx = means[g * 3 + 0], my = means[g * 3 + 1], mz = means[g * 3 + 2];
    float rx = 3.0f * sqrtf(a), ry = 3.0f * sqrtf(d), rz = 3.0f * sqrtf(f);
    // trunc-toward-zero matches .astype(int32)
    int sx = max(0, (int)((mx - rx - VMINX) / VS));
    int sy = max(0, (int)((my - ry - VMINY) / VS));
    int sz = max(0, (int)((mz - rz - VMINZ) / VS));
    int ex = min(GX, (int)((mx + rx - VMINX) / VS) + 1); ex = min(ex, sx + KW);
    int ey = min(GY, (int)((my + ry - VMINY) / VS) + 1); ey = min(ey, sy + KW);
    int ez = min(GZ, (int)((mz + rz - VMINZ) / VS) + 1); ez = min(ez, sz + KW);

    float* r = gdata + (size_t)g * REC;
    r[0] = mx; r[1] = my; r[2] = mz;
    r[3] = A * invdet;                 // i00
    r[4] = B * invdet;                 // i01
    r[5] = C * invdet;                 // i02
    r[6] = (a * f - c * c) * invdet;   // i11
    r[7] = (b * c - a * e) * invdet;   // i12
    r[8] = (a * d - b * b) * invdet;   // i22
    r[9] = opac[g];
#pragma unroll
    for (int k = 0; k < ND; ++k) r[10 + k] = feats[(size_t)g * ND + k];
    r[26] = __int_as_float(sx); r[27] = __int_as_float(sy); r[28] = __int_as_float(sz);
    r[29] = __int_as_float(ex); r[30] = __int_as_float(ey); r[31] = __int_as_float(ez);

    int tx0 = sx >> 3, tx1 = (ex - 1) >> 3;
    int ty0 = sy >> 3, ty1 = (ey - 1) >> 3;
    int tz0 = sz >> 3, tz1 = (ez - 1) >> 3;
    for (int tx = tx0; tx <= tx1; ++tx)
        for (int ty = ty0; ty <= ty1; ++ty)
            for (int tz = tz0; tz <= tz1; ++tz)
                atomicAdd(&counts[(tx * TY + ty) * TZ + tz], 1);
}

// Exclusive prefix sum over NT=1250 counts; single block of 256, 5 elems/thread.
__global__ __launch_bounds__(256) void gv_scan(
    const int* __restrict__ counts, int* __restrict__ offsets, int* __restrict__ cursors)
{
    __shared__ int s[256];
    int t = threadIdx.x;
    int base = t * 5;
    int loc[5];
    int sum = 0;
#pragma unroll
    for (int k = 0; k < 5; ++k) {
        int idx = base + k;
        loc[k] = sum;
        int c = (idx < NT) ? counts[idx] : 0;
        sum += c;
    }
    s[t] = sum;
    __syncthreads();
    for (int off = 1; off < 256; off <<= 1) {
        int v = (t >= off) ? s[t - off] : 0;
        __syncthreads();
        s[t] += v;
        __syncthreads();
    }
    int excl = (t > 0) ? s[t - 1] : 0;
#pragma unroll
    for (int k = 0; k < 5; ++k) {
        int idx = base + k;
        if (idx < NT) {
            int o = excl + loc[k];
            offsets[idx] = o;
            cursors[idx] = o;
        }
    }
    if (t == 255) offsets[NT] = s[255];
}

// Scatter gaussian ids into per-tile contiguous entry lists.
__global__ __launch_bounds__(256) void gv_scatter(
    const float* __restrict__ gdata, int* __restrict__ cursors,
    int* __restrict__ entries, int n)
{
    int g = blockIdx.x * 256 + threadIdx.x;
    if (g >= n) return;
    const float* r = gdata + (size_t)g * REC;
    int sx = __float_as_int(r[26]), sy = __float_as_int(r[27]), sz = __float_as_int(r[28]);
    int ex = __float_as_int(r[29]), ey = __float_as_int(r[30]), ez = __float_as_int(r[31]);
    int tx0 = sx >> 3, tx1 = (ex - 1) >> 3;
    int ty0 = sy >> 3, ty1 = (ey - 1) >> 3;
    int tz0 = sz >> 3, tz1 = (ez - 1) >> 3;
    for (int tx = tx0; tx <= tx1; ++tx)
        for (int ty = ty0; ty <= ty1; ++ty)
            for (int tz = tz0; tz <= tz1; ++tz) {
                int slot = atomicAdd(&cursors[(tx * TY + ty) * TZ + tz], 1);
                entries[slot] = g;
            }
}

// One block per 8x8x8 tile. Each thread owns VPT=2 voxels; accumulates density +
// 16 feature channels in registers; loops over the tile's gaussian entries with
// record data forced into SGPRs (uniform per block). Writes each voxel once,
// fused with normalization -> no global atomics, no init/norm kernels.
__global__ __launch_bounds__(256) void gv_tile(
    const float* __restrict__ gdata, const int* __restrict__ offsets,
    const int* __restrict__ entries, float* __restrict__ out)
{
    const int b  = blockIdx.x;
    const int tz = b % TZ;
    const int ty = (b / TZ) % TY;
    const int tx = b / (TZ * TY);
    const int t  = threadIdx.x;

    int ixv[VPT], iyv[VPT], izv[VPT];
    float pxc[VPT], pyc[VPT], pzc[VPT];
#pragma unroll
    for (int v = 0; v < VPT; ++v) {
        int vi = v * 256 + t;              // 0..511
        int lx = vi >> 6;                  // 0..7
        int ly = (vi >> 3) & 7;
        int lz = vi & 7;
        ixv[v] = tx * TS + lx;
        iyv[v] = ty * TS + ly;
        izv[v] = tz * TS + lz;
        pxc[v] = (float)ixv[v] * VS + VMINX;  // voxel CORNER coords
        pyc[v] = (float)iyv[v] * VS + VMINY;
        pzc[v] = (float)izv[v] * VS + VMINZ;
    }

    float accd[VPT];
    float accf[VPT][ND];
#pragma unroll
    for (int v = 0; v < VPT; ++v) {
        accd[v] = 0.0f;
#pragma unroll
        for (int c = 0; c < ND; ++c) accf[v][c] = 0.0f;
        accf[v][ND - 1] = 1e-5f;           // reference: grid_feats[:, -1] = 1e-5
    }

    const int o0 = offsets[b], o1 = offsets[b + 1];
    for (int e = o0; e < o1; ++e) {
        // Force the entry id scalar so record loads become s_load (SGPR broadcast).
        int ge = __builtin_amdgcn_readfirstlane(entries[e]);
        const float* __restrict__ r = gdata + (size_t)ge * REC;
        float mx = r[0], my = r[1], mz = r[2];
        float i00 = r[3], i01 = r[4], i02 = r[5];
        float i11 = r[6], i12 = r[7], i22 = r[8];
        float op  = r[9];
        float fr[ND];
#pragma unroll
        for (int c = 0; c < ND; ++c) fr[c] = r[10 + c];
        int sx = __float_as_int(r[26]), sy = __float_as_int(r[27]), sz = __float_as_int(r[28]);
        int ex = __float_as_int(r[29]), ey = __float_as_int(r[30]), ez = __float_as_int(r[31]);

#pragma unroll
        for (int v = 0; v < VPT; ++v) {
            bool in = (ixv[v] >= sx) & (ixv[v] < ex)
                    & (iyv[v] >= sy) & (iyv[v] < ey)
                    & (izv[v] >= sz) & (izv[v] < ez);
            if (in) {
                float px = pxc[v] - mx;
                float py = pyc[v] - my;
                float pz = pzc[v] - mz;
                float mahal = i00 * px * px + i11 * py * py + i22 * pz * pz
                            + 2.0f * (i01 * px * py + i02 * px * pz + i12 * py * pz);
                float dens = op * __expf(-0.5f * mahal);
                accd[v] += dens;
#pragma unroll
                for (int c = 0; c < ND; ++c) accf[v][c] += dens * fr[c];
            }
        }
    }

    // Epilogue: write density (raw) + normalized features; each voxel exactly once.
#pragma unroll
    for (int v = 0; v < VPT; ++v) {
        int flat = (ixv[v] * GY + iyv[v]) * GZ + izv[v];
        out[flat] = accd[v];
        float inv = 1.0f / fmaxf(accd[v], 1e-6f);   // clip(density, 1e-6, None)
        float4* fo = (float4*)(out + TOTAL + (size_t)flat * ND);
#pragma unroll
        for (int q = 0; q < 4; ++q) {
            float4 w;
            w.x = accf[v][q * 4 + 0] * inv;
            w.y = accf[v][q * 4 + 1] * inv;
            w.z = accf[v][q * 4 + 2] * inv;
            w.w = accf[v][q * 4 + 3] * inv;
            fo[q] = w;
        }
    }
}

extern "C" void kernel_launch(void* const* d_in, const int* in_sizes, int n_in,
                              void* d_out, int out_size, void* d_ws, size_t ws_size,
                              hipStream_t stream) {
    const float* means = (const float*)d_in[0];   // [N,3]
    const float* covs  = (const float*)d_in[1];   // [N,3,3]
    const float* opac  = (const float*)d_in[2];   // [N]
    const float* feats = (const float*)d_in[3];   // [N,16]
    float* out = (float*)d_out;                   // [TOTAL + TOTAL*ND]
    const int n = in_sizes[2];

    // Workspace carve-up (all regions re-poisoned each call; we init what we use).
    float* gdata   = (float*)d_ws;                            // n*REC floats
    int*   counts  = (int*)(gdata + (size_t)n * REC);         // NT
    int*   offsets = counts + ((NT + 63) & ~63);              // NT+1
    int*   cursors = offsets + ((NT + 1 + 63) & ~63);         // NT
    int*   entries = cursors + ((NT + 63) & ~63);             // up to 8n

    gv_zero<<<(NT + 255) / 256, 256, 0, stream>>>(counts);
    gv_prep<<<(n + 255) / 256, 256, 0, stream>>>(means, covs, opac, feats, gdata, counts, n);
    gv_scan<<<1, 256, 0, stream>>>(counts, offsets, cursors);
    gv_scatter<<<(n + 255) / 256, 256, 0, stream>>>(gdata, cursors, entries, n);
    gv_tile<<<NT, 256, 0, stream>>>(gdata, offsets, entries, out);
}

// Round 3
// 141.062 us; speedup vs baseline: 8.5634x; 1.0384x over previous
//
#include <hip/hip_runtime.h>
#include <math.h>

// Problem constants (Occ3D-nuScenes volume)
constexpr int   GX = 200, GY = 200, GZ = 16;
constexpr int   TOTAL = GX * GY * GZ;        // 640000 voxels
constexpr int   ND = 16;                     // feature dims
constexpr int   KW = 6;                      // reference window: start + [0,6)
constexpr float VS = 0.4f;
constexpr float VMINX = -40.0f, VMINY = -40.0f, VMINZ = -1.0f;

// Tiling: 4x4x4 voxel tiles, one wave (64 threads) per tile, 1 voxel/thread.
constexpr int   TS = 4;
constexpr int   TX = 50, TY = 50, TZ = 4;    // 200/4, 200/4, 16/4
constexpr int   NT = TX * TY * TZ;           // 10000 tiles
constexpr int   REC = 32;                    // floats per packed gaussian record
constexpr int   CAP = 256;                   // per-tile entry capacity (lambda~13)

// d_out layout: [density: TOTAL floats][feats: TOTAL*ND floats]
// d_ws layout:  [gdata: n*REC floats][counts: NT ints][entries: NT*CAP ints]

// Fused per-gaussian precompute + tile binning (fixed-capacity lists -> no scan).
__global__ __launch_bounds__(64) void gv_prep(
    const float* __restrict__ means, const float* __restrict__ covs,
    const float* __restrict__ opac,  const float* __restrict__ feats,
    float* __restrict__ gdata, int* __restrict__ counts,
    int* __restrict__ entries, int n)
{
    int g = blockIdx.x * 64 + threadIdx.x;
    if (g >= n) return;
    const float* cv = covs + (size_t)g * 9;
    // symmetric 3x3: [[a,b,c],[b,d,e],[c,e,f]]
    float a = cv[0], b = cv[1], c = cv[2], d = cv[4], e = cv[5], f = cv[8];
    float A = d * f - e * e;
    float B = c * e - b * f;
    float C = b * e - c * d;
    float invdet = 1.0f / (a * A + b * B + c * C);
    float mx = means[g * 3 + 0], my = means[g * 3 + 1], mz = means[g * 3 + 2];
    float rx = 3.0f * sqrtf(a), ry = 3.0f * sqrtf(d), rz = 3.0f * sqrtf(f);
    // trunc-toward-zero matches .astype(int32)
    int sx = max(0, (int)((mx - rx - VMINX) / VS));
    int sy = max(0, (int)((my - ry - VMINY) / VS));
    int sz = max(0, (int)((mz - rz - VMINZ) / VS));
    // reference window is start + [0,KW) masked by end -> clamp end to start+KW
    int ex = min(GX, (int)((mx + rx - VMINX) / VS) + 1); ex = min(ex, sx + KW);
    int ey = min(GY, (int)((my + ry - VMINY) / VS) + 1); ey = min(ey, sy + KW);
    int ez = min(GZ, (int)((mz + rz - VMINZ) / VS) + 1); ez = min(ez, sz + KW);

    float rec[REC];
    rec[0] = mx; rec[1] = my; rec[2] = mz;
    rec[3] = A * invdet;                 // i00
    rec[4] = B * invdet;                 // i01
    rec[5] = C * invdet;                 // i02
    rec[6] = (a * f - c * c) * invdet;   // i11
    rec[7] = (b * c - a * e) * invdet;   // i12
    rec[8] = (a * d - b * b) * invdet;   // i22
    rec[9] = opac[g];
    const float4* f4 = (const float4*)(feats + (size_t)g * ND);
#pragma unroll
    for (int q = 0; q < 4; ++q) {
        float4 v = f4[q];
        rec[10 + q * 4 + 0] = v.x; rec[10 + q * 4 + 1] = v.y;
        rec[10 + q * 4 + 2] = v.z; rec[10 + q * 4 + 3] = v.w;
    }
    rec[26] = __int_as_float(sx); rec[27] = __int_as_float(sy); rec[28] = __int_as_float(sz);
    rec[29] = __int_as_float(ex); rec[30] = __int_as_float(ey); rec[31] = __int_as_float(ez);
    float4* dst = (float4*)(gdata + (size_t)g * REC);   // 128B-aligned
#pragma unroll
    for (int q = 0; q < 8; ++q) dst[q] = ((const float4*)rec)[q];

    int tx0 = sx >> 2, tx1 = (ex - 1) >> 2;
    int ty0 = sy >> 2, ty1 = (ey - 1) >> 2;
    int tz0 = sz >> 2, tz1 = (ez - 1) >> 2;
    for (int tx = tx0; tx <= tx1; ++tx)
        for (int ty = ty0; ty <= ty1; ++ty)
            for (int tz = tz0; tz <= tz1; ++tz) {
                int tile = (tx * TY + ty) * TZ + tz;
                int slot = atomicAdd(&counts[tile], 1);
                if (slot < CAP) entries[(size_t)tile * CAP + slot] = g;
            }
}

// One wave per 4x4x4 tile; each thread owns 1 voxel (17 register accumulators).
// Records broadcast via readfirstlane -> s_load. Each voxel written exactly once
// with normalization fused -> no global atomics, no separate init/norm passes.
__global__ __launch_bounds__(64) void gv_tile(
    const float* __restrict__ gdata, const int* __restrict__ counts,
    const int* __restrict__ entries, float* __restrict__ out)
{
    const int b  = blockIdx.x;
    const int tz = b % TZ;
    const int ty = (b / TZ) % TY;
    const int tx = b / (TZ * TY);
    const int t  = threadIdx.x;

    const int lz = t & 3, ly = (t >> 2) & 3, lx = t >> 4;
    const int ix = tx * TS + lx, iy = ty * TS + ly, iz = tz * TS + lz;
    const float pxc = (float)ix * VS + VMINX;   // voxel CORNER coords
    const float pyc = (float)iy * VS + VMINY;
    const float pzc = (float)iz * VS + VMINZ;

    float accd = 0.0f;
    float accf[ND];
#pragma unroll
    for (int c = 0; c < ND; ++c) accf[c] = 0.0f;
    accf[ND - 1] = 1e-5f;                       // reference: grid_feats[:, -1] = 1e-5

    const int cnt = min(counts[b], CAP);
    const int* __restrict__ el = entries + (size_t)b * CAP;

    for (int e = 0; e < cnt; ++e) {
        // e and el are uniform; force scalar so record loads are s_load broadcasts.
        int ge = __builtin_amdgcn_readfirstlane(el[e]);
        const float* __restrict__ r = gdata + (size_t)ge * REC;
        int sx = __float_as_int(r[26]), sy = __float_as_int(r[27]), sz = __float_as_int(r[28]);
        int ex = __float_as_int(r[29]), ey = __float_as_int(r[30]), ez = __float_as_int(r[31]);
        bool in = (ix >= sx) & (ix < ex)
                & (iy >= sy) & (iy < ey)
                & (iz >= sz) & (iz < ez);
        if (in) {
            float px = pxc - r[0];
            float py = pyc - r[1];
            float pz = pzc - r[2];
            float mahal = r[3] * px * px + r[6] * py * py + r[8] * pz * pz
                        + 2.0f * (r[4] * px * py + r[5] * px * pz + r[7] * py * pz);
            float dens = r[9] * __expf(-0.5f * mahal);
            accd += dens;
#pragma unroll
            for (int c = 0; c < ND; ++c) accf[c] = fmaf(dens, r[10 + c], accf[c]);
        }
    }

    // Epilogue: density (raw) + normalized features; each voxel exactly once.
    const int flat = (ix * GY + iy) * GZ + iz;
    out[flat] = accd;
    float inv = 1.0f / fmaxf(accd, 1e-6f);      // clip(density, 1e-6, None)
    float4* fo = (float4*)(out + TOTAL + (size_t)flat * ND);
#pragma unroll
    for (int q = 0; q < 4; ++q) {
        float4 w;
        w.x = accf[q * 4 + 0] * inv;
        w.y = accf[q * 4 + 1] * inv;
        w.z = accf[q * 4 + 2] * inv;
        w.w = accf[q * 4 + 3] * inv;
        fo[q] = w;
    }
}

extern "C" void kernel_launch(void* const* d_in, const int* in_sizes, int n_in,
                              void* d_out, int out_size, void* d_ws, size_t ws_size,
                              hipStream_t stream) {
    const float* means = (const float*)d_in[0];   // [N,3]
    const float* covs  = (const float*)d_in[1];   // [N,3,3]
    const float* opac  = (const float*)d_in[2];   // [N]
    const float* feats = (const float*)d_in[3];   // [N,16]
    float* out = (float*)d_out;                   // [TOTAL + TOTAL*ND]
    const int n = in_sizes[2];

    float* gdata   = (float*)d_ws;                            // n*REC floats (4 MB)
    int*   counts  = (int*)(gdata + (size_t)n * REC);         // NT ints
    int*   entries = counts + ((NT + 63) & ~63);              // NT*CAP ints (10.24 MB)

    hipMemsetAsync(counts, 0, NT * sizeof(int), stream);
    gv_prep<<<(n + 63) / 64, 64, 0, stream>>>(means, covs, opac, feats,
                                              gdata, counts, entries, n);
    gv_tile<<<NT, 64, 0, stream>>>(gdata, counts, entries, out);
}

// Round 4
// 108.756 us; speedup vs baseline: 11.1072x; 1.2971x over previous
//
#include <hip/hip_runtime.h>
#include <math.h>

// Problem constants (Occ3D-nuScenes volume)
constexpr int   GX = 200, GY = 200, GZ = 16;
constexpr int   TOTAL = GX * GY * GZ;        // 640000 voxels
constexpr int   ND = 16;                     // feature dims
constexpr int   KW = 6;                      // reference window: start + [0,6)
constexpr float VS = 0.4f;
constexpr float VMINX = -40.0f, VMINY = -40.0f, VMINZ = -1.0f;

// Tiling: 4x4x4 voxel tiles; one WAVE per tile; block = (tx,ty) x 4 tz-waves.
constexpr int   TS = 4;
constexpr int   TX = 50, TY = 50, TZ = 4;    // 200/4, 200/4, 16/4
constexpr int   NT = TX * TY * TZ;           // 10000 tiles
constexpr int   REC = 32;                    // floats per packed gaussian record
constexpr int   CAP = 128;                   // per-tile entry capacity (lambda~13, max~50)
constexpr float NHL2E = -0.72134752044448170f; // -0.5 * log2(e): folds exp(-0.5*m) -> exp2(q)

// d_out layout: [density: TOTAL floats][feats: TOTAL*ND floats]
// d_ws layout:  [gdata: n*REC floats][counts: NT ints][entries: NT*CAP ints]

// Fused per-gaussian precompute + tile binning (fixed-capacity lists -> no scan).
// Stores inverse covariance pre-scaled by -0.5*log2(e), off-diagonals pre-doubled.
__global__ __launch_bounds__(256) void gv_prep(
    const float* __restrict__ means, const float* __restrict__ covs,
    const float* __restrict__ opac,  const float* __restrict__ feats,
    float* __restrict__ gdata, int* __restrict__ counts,
    int* __restrict__ entries, int n)
{
    int g = blockIdx.x * 256 + threadIdx.x;
    if (g >= n) return;
    const float* cv = covs + (size_t)g * 9;
    // symmetric 3x3: [[a,b,c],[b,d,e],[c,e,f]]
    float a = cv[0], b = cv[1], c = cv[2], d = cv[4], e = cv[5], f = cv[8];
    float A = d * f - e * e;
    float B = c * e - b * f;
    float C = b * e - c * d;
    float invdet = 1.0f / (a * A + b * B + c * C);
    float mx = means[g * 3 + 0], my = means[g * 3 + 1], mz = means[g * 3 + 2];
    float rx = 3.0f * sqrtf(a), ry = 3.0f * sqrtf(d), rz = 3.0f * sqrtf(f);
    // trunc-toward-zero matches .astype(int32)
    int sx = max(0, (int)((mx - rx - VMINX) / VS));
    int sy = max(0, (int)((my - ry - VMINY) / VS));
    int sz = max(0, (int)((mz - rz - VMINZ) / VS));
    // reference window is start + [0,KW) masked by end -> clamp end to start+KW
    int ex = min(GX, (int)((mx + rx - VMINX) / VS) + 1); ex = min(ex, sx + KW);
    int ey = min(GY, (int)((my + ry - VMINY) / VS) + 1); ey = min(ey, sy + KW);
    int ez = min(GZ, (int)((mz + rz - VMINZ) / VS) + 1); ez = min(ez, sz + KW);

    float rec[REC];
    rec[0] = mx; rec[1] = my; rec[2] = mz;
    rec[3] = (A * invdet) * NHL2E;                    // q00
    rec[4] = (B * invdet) * (2.0f * NHL2E);           // q01 (doubled)
    rec[5] = (C * invdet) * (2.0f * NHL2E);           // q02 (doubled)
    rec[6] = ((a * f - c * c) * invdet) * NHL2E;      // q11
    rec[7] = ((b * c - a * e) * invdet) * (2.0f * NHL2E); // q12 (doubled)
    rec[8] = ((a * d - b * b) * invdet) * NHL2E;      // q22
    rec[9] = opac[g];
    const float4* f4 = (const float4*)(feats + (size_t)g * ND);
#pragma unroll
    for (int q = 0; q < 4; ++q) {
        float4 v = f4[q];
        rec[10 + q * 4 + 0] = v.x; rec[10 + q * 4 + 1] = v.y;
        rec[10 + q * 4 + 2] = v.z; rec[10 + q * 4 + 3] = v.w;
    }
    rec[26] = __int_as_float(sx); rec[27] = __int_as_float(sy); rec[28] = __int_as_float(sz);
    rec[29] = __int_as_float(ex); rec[30] = __int_as_float(ey); rec[31] = __int_as_float(ez);
    float4* dst = (float4*)(gdata + (size_t)g * REC);   // 128B-aligned
#pragma unroll
    for (int q = 0; q < 8; ++q) dst[q] = ((const float4*)rec)[q];

    int tx0 = sx >> 2, tx1 = (ex - 1) >> 2;
    int ty0 = sy >> 2, ty1 = (ey - 1) >> 2;
    int tz0 = sz >> 2, tz1 = (ez - 1) >> 2;
    for (int tx = tx0; tx <= tx1; ++tx)
        for (int ty = ty0; ty <= ty1; ++ty)
            for (int tz = tz0; tz <= tz1; ++tz) {
                int tile = (tx * TY + ty) * TZ + tz;
                int slot = atomicAdd(&counts[tile], 1);
                if (slot < CAP) entries[(size_t)tile * CAP + slot] = g;
            }
}

struct GRec {
    float mx, my, mz;
    float q00, q01, q02, q11, q12, q22;
    float op;
    float fr[ND];
    int sx, sy, sz, ex, ey, ez;
};

__device__ __forceinline__ GRec load_rec(const float* __restrict__ r) {
    GRec g;
    g.mx = r[0]; g.my = r[1]; g.mz = r[2];
    g.q00 = r[3]; g.q01 = r[4]; g.q02 = r[5];
    g.q11 = r[6]; g.q12 = r[7]; g.q22 = r[8];
    g.op  = r[9];
#pragma unroll
    for (int c = 0; c < ND; ++c) g.fr[c] = r[10 + c];
    g.sx = __float_as_int(r[26]); g.sy = __float_as_int(r[27]); g.sz = __float_as_int(r[28]);
    g.ex = __float_as_int(r[29]); g.ey = __float_as_int(r[30]); g.ez = __float_as_int(r[31]);
    return g;
}

// One WAVE per 4x4x4 tile (1 voxel/lane, 17 register accumulators). Block of 256
// = 4 waves covering the tz column of one (tx,ty) cell. Entry records are
// broadcast (uniform address -> s_load) with a manual 2-deep software pipeline:
// entry id prefetched 2 iterations ahead, full record 1 iteration ahead, so the
// el->record load chain is hidden behind compute. Each voxel written exactly
// once with normalization fused -> no global atomics, no init/norm passes.
__global__ __launch_bounds__(256) void gv_tile(
    const float* __restrict__ gdata, const int* __restrict__ counts,
    const int* __restrict__ entries, float* __restrict__ out)
{
    const int blk  = blockIdx.x;          // 0..2499 = tx*TY+ty
    const int ty   = blk % TY;
    const int tx   = blk / TY;
    const int tz   = threadIdx.x >> 6;    // wave id = tz tile
    const int lane = threadIdx.x & 63;
    const int tile = (tx * TY + ty) * TZ + tz;

    const int lz = lane & 3, ly = (lane >> 2) & 3, lx = lane >> 4;
    const int ix = tx * TS + lx, iy = ty * TS + ly, iz = tz * TS + lz;
    const float pxc = (float)ix * VS + VMINX;   // voxel CORNER coords
    const float pyc = (float)iy * VS + VMINY;
    const float pzc = (float)iz * VS + VMINZ;

    float accd = 0.0f;
    float accf[ND];
#pragma unroll
    for (int c = 0; c < ND; ++c) accf[c] = 0.0f;
    accf[ND - 1] = 1e-5f;                       // reference: grid_feats[:, -1] = 1e-5

    const int cnt = min(counts[tile], CAP);     // wave-uniform
    const int* __restrict__ el = entries + (size_t)tile * CAP;

    if (cnt > 0) {
        int id0 = __builtin_amdgcn_readfirstlane(el[0]);
        GRec cur = load_rec(gdata + (size_t)id0 * REC);
        int idn = __builtin_amdgcn_readfirstlane(el[cnt > 1 ? 1 : 0]);
        for (int e = 0; e < cnt; ++e) {
            // prefetch: entry id 2 ahead, record 1 ahead
            int e2  = (e + 2 < cnt) ? (e + 2) : (cnt - 1);
            int id2 = __builtin_amdgcn_readfirstlane(el[e2]);
            GRec nxt = load_rec(gdata + (size_t)idn * REC);

            bool in = (ix >= cur.sx) & (ix < cur.ex)
                    & (iy >= cur.sy) & (iy < cur.ey)
                    & (iz >= cur.sz) & (iz < cur.ez);
            if (in) {
                float px = pxc - cur.mx;
                float py = pyc - cur.my;
                float pz = pzc - cur.mz;
                float q = cur.q00 * px * px + cur.q11 * py * py + cur.q22 * pz * pz
                        + cur.q01 * px * py + cur.q02 * px * pz + cur.q12 * py * pz;
                float dens = cur.op * __builtin_amdgcn_exp2f(q);  // = op*exp(-0.5*mahal)
                accd += dens;
#pragma unroll
                for (int c = 0; c < ND; ++c) accf[c] = fmaf(dens, cur.fr[c], accf[c]);
            }
            cur = nxt;
            idn = id2;
        }
    }

    // Epilogue: density (raw) + normalized features; each voxel exactly once.
    const int flat = (ix * GY + iy) * GZ + iz;
    out[flat] = accd;
    float inv = 1.0f / fmaxf(accd, 1e-6f);      // clip(density, 1e-6, None)
    float4* fo = (float4*)(out + TOTAL + (size_t)flat * ND);
#pragma unroll
    for (int q = 0; q < 4; ++q) {
        float4 w;
        w.x = accf[q * 4 + 0] * inv;
        w.y = accf[q * 4 + 1] * inv;
        w.z = accf[q * 4 + 2] * inv;
        w.w = accf[q * 4 + 3] * inv;
        fo[q] = w;
    }
}

extern "C" void kernel_launch(void* const* d_in, const int* in_sizes, int n_in,
                              void* d_out, int out_size, void* d_ws, size_t ws_size,
                              hipStream_t stream) {
    const float* means = (const float*)d_in[0];   // [N,3]
    const float* covs  = (const float*)d_in[1];   // [N,3,3]
    const float* opac  = (const float*)d_in[2];   // [N]
    const float* feats = (const float*)d_in[3];   // [N,16]
    float* out = (float*)d_out;                   // [TOTAL + TOTAL*ND]
    const int n = in_sizes[2];

    float* gdata   = (float*)d_ws;                            // n*REC floats (4 MB)
    int*   counts  = (int*)(gdata + (size_t)n * REC);         // NT ints
    int*   entries = counts + ((NT + 63) & ~63);              // NT*CAP ints (5.12 MB)

    hipMemsetAsync(counts, 0, NT * sizeof(int), stream);
    gv_prep<<<(n + 255) / 256, 256, 0, stream>>>(means, covs, opac, feats,
                                                 gdata, counts, entries, n);
    gv_tile<<<TX * TY, 256, 0, stream>>>(gdata, counts, entries, out);
}